// Round 1
// baseline (23278.308 us; speedup 1.0000x reference)
//
#include <hip/hip_runtime.h>

typedef short bf16x8 __attribute__((ext_vector_type(8)));
typedef float f32x4 __attribute__((ext_vector_type(4)));

// round-to-nearest-even f32 -> bf16, packed pair into u32
__device__ __forceinline__ unsigned pack2bf(float a, float b) {
  union { float f; unsigned u; } x, y;
  x.f = a; y.f = b;
  unsigned ra = (x.u + 0x7FFFu + ((x.u >> 16) & 1u)) >> 16;
  unsigned rb = (y.u + 0x7FFFu + ((y.u >> 16) & 1u)) & 0xFFFF0000u;
  return ra | rb;
}

#define KB 64
#define LDSP 72  // padded LDS row (bf16 elems): 144B stride, 16B aligned, conflict-benign

// C[m][n] = sum_k A[m][k] * W[g0+n][k] + bias[g0+n]
// A rows: 768-stride f32.  out rows: 2304-stride f32.
// grid.x = N-tiles (2304/64 = 36), grid.y = batch (A0 += y*a_bstride, out += y*o_bstride)
__global__ __launch_bounds__(256) void gemm_bt(
    const float* __restrict__ A0, size_t a_bstride,
    const float* __restrict__ W,
    const float* __restrict__ bias,
    float* __restrict__ out, size_t o_bstride,
    int Mvalid)
{
  __shared__ unsigned short As[64][LDSP];
  __shared__ unsigned short Bs[64][LDSP];
  const int tid = threadIdx.x;
  const int g0 = blockIdx.x * 64;
  const float* Ab = A0 + (size_t)blockIdx.y * a_bstride;
  float* outb = out + (size_t)blockIdx.y * o_bstride;

  const int srow = tid >> 2;          // staging row 0..63
  const int scol = (tid & 3) << 4;    // staging col 0,16,32,48
  const int wv = tid >> 6;
  const int lane = tid & 63;
  const int wr = wv >> 1, wc = wv & 1;
  const int lrow = lane & 15;
  const int lk = (lane >> 4) << 3;

  f32x4 acc[2][2];
#pragma unroll
  for (int i = 0; i < 2; ++i)
#pragma unroll
    for (int j = 0; j < 2; ++j)
      acc[i][j] = (f32x4){0.f, 0.f, 0.f, 0.f};

  const float* Aptr = Ab + (size_t)srow * 768 + scol;
  const float* Bptr = W + ((size_t)(g0 + srow)) * 768 + scol;
  const bool aval = srow < Mvalid;

  for (int k0 = 0; k0 < 768; k0 += KB) {
    uint4 ua0, ua1, ub0, ub1;
    if (aval) {
      const float4* qa = (const float4*)(Aptr + k0);
      float4 f0 = qa[0], f1 = qa[1], f2 = qa[2], f3 = qa[3];
      ua0 = make_uint4(pack2bf(f0.x, f0.y), pack2bf(f0.z, f0.w),
                       pack2bf(f1.x, f1.y), pack2bf(f1.z, f1.w));
      ua1 = make_uint4(pack2bf(f2.x, f2.y), pack2bf(f2.z, f2.w),
                       pack2bf(f3.x, f3.y), pack2bf(f3.z, f3.w));
    } else {
      ua0 = make_uint4(0u, 0u, 0u, 0u);
      ua1 = ua0;
    }
    {
      const float4* qb = (const float4*)(Bptr + k0);
      float4 f0 = qb[0], f1 = qb[1], f2 = qb[2], f3 = qb[3];
      ub0 = make_uint4(pack2bf(f0.x, f0.y), pack2bf(f0.z, f0.w),
                       pack2bf(f1.x, f1.y), pack2bf(f1.z, f1.w));
      ub1 = make_uint4(pack2bf(f2.x, f2.y), pack2bf(f2.z, f2.w),
                       pack2bf(f3.x, f3.y), pack2bf(f3.z, f3.w));
    }
    __syncthreads();  // protect LDS from previous iteration's readers
    *(uint4*)&As[srow][scol] = ua0;
    *(uint4*)&As[srow][scol + 8] = ua1;
    *(uint4*)&Bs[srow][scol] = ub0;
    *(uint4*)&Bs[srow][scol + 8] = ub1;
    __syncthreads();
#pragma unroll
    for (int kh = 0; kh < 2; ++kh) {
      bf16x8 a0 = *(const bf16x8*)&As[32 * wr + lrow][32 * kh + lk];
      bf16x8 a1 = *(const bf16x8*)&As[32 * wr + 16 + lrow][32 * kh + lk];
      bf16x8 b0 = *(const bf16x8*)&Bs[32 * wc + lrow][32 * kh + lk];
      bf16x8 b1 = *(const bf16x8*)&Bs[32 * wc + 16 + lrow][32 * kh + lk];
      acc[0][0] = __builtin_amdgcn_mfma_f32_16x16x32_bf16(a0, b0, acc[0][0], 0, 0, 0);
      acc[0][1] = __builtin_amdgcn_mfma_f32_16x16x32_bf16(a0, b1, acc[0][1], 0, 0, 0);
      acc[1][0] = __builtin_amdgcn_mfma_f32_16x16x32_bf16(a1, b0, acc[1][0], 0, 0, 0);
      acc[1][1] = __builtin_amdgcn_mfma_f32_16x16x32_bf16(a1, b1, acc[1][1], 0, 0, 0);
    }
  }

  const int lgrp = lane >> 4;
#pragma unroll
  for (int fr = 0; fr < 2; ++fr)
#pragma unroll
    for (int fc = 0; fc < 2; ++fc)
#pragma unroll
      for (int j = 0; j < 4; ++j) {
        int m = 32 * wr + 16 * fr + lgrp * 4 + j;
        int n = 32 * wc + 16 * fc + lrow;
        if (m < Mvalid)
          outb[(size_t)m * 2304 + g0 + n] = acc[fr][fc][j] + bias[g0 + n];
      }
}

template <int N>
__device__ __forceinline__ void blk_reduce(float* v, float* lds) {
#pragma unroll
  for (int k = 0; k < N; ++k) {
    float x = v[k];
#pragma unroll
    for (int off = 1; off < 64; off <<= 1) x += __shfl_xor(x, off);
    v[k] = x;
  }
  const int wv = threadIdx.x >> 6;
  const int lane = threadIdx.x & 63;
  if (lane == 0) {
#pragma unroll
    for (int k = 0; k < N; ++k) lds[wv * N + k] = v[k];
  }
  __syncthreads();
#pragma unroll
  for (int k = 0; k < N; ++k)
    v[k] = lds[k] + lds[N + k] + lds[2 * N + k] + lds[3 * N + k];
  __syncthreads();
}

// One workgroup per batch element; 256 threads; 3 h-indices per thread.
__global__ __launch_bounds__(256) void step_update(
    const float* __restrict__ hg,   // [64][2304]
    const float* __restrict__ xg,   // [64][chunk][2304]
    int tt, int chunk,
    const float* __restrict__ lw,   // [3][768]
    const float* __restrict__ lb,
    float* __restrict__ hcur,       // [64][768]
    const float* res,               // residual [64][512][768] (may alias seq)
    float* seq,                     // d_out seq region [64][512][768]
    int t,
    float* __restrict__ hfin,       // d_out tail for this layer [64][768]
    int is_last)
{
  __shared__ float lds[16];
  const int b = blockIdx.x;
  const int tid = threadIdx.x;
  const float* hgb = hg + (size_t)b * 2304;
  const float* xgb = xg + ((size_t)b * chunk + tt) * 2304;

  float hn[3], xn[3], s1[3], s2[3];
  float sum1 = 0.f, sq1 = 0.f, sum2 = 0.f, sq2 = 0.f;
#pragma unroll
  for (int p = 0; p < 3; ++p) {
    int i = tid + (p << 8);
    float hr = hgb[i], hz = hgb[768 + i];
    hn[p] = hgb[1536 + i];
    float xr = xgb[i], xz = xgb[768 + i];
    xn[p] = xgb[1536 + i];
    s1[p] = xr + hr;
    s2[p] = xz + hz;
    sum1 += s1[p]; sq1 += s1[p] * s1[p];
    sum2 += s2[p]; sq2 += s2[p] * s2[p];
  }
  float v4[4] = {sum1, sq1, sum2, sq2};
  blk_reduce<4>(v4, lds);
  const float inv = 1.0f / 768.0f;
  float mu1 = v4[0] * inv, var1 = v4[1] * inv - mu1 * mu1;
  float mu2 = v4[2] * inv, var2 = v4[3] * inv - mu2 * mu2;
  float rs1 = rsqrtf(var1 + 1e-5f);
  float rs2 = rsqrtf(var2 + 1e-5f);

  float z[3], m[3];
  float sm = 0.f, sq = 0.f;
#pragma unroll
  for (int p = 0; p < 3; ++p) {
    int i = tid + (p << 8);
    float rn = (s1[p] - mu1) * rs1 * lw[i] + lb[i];
    float r = 1.f / (1.f + __expf(-rn));
    float zn = (s2[p] - mu2) * rs2 * lw[768 + i] + lb[768 + i];
    z[p] = 1.f / (1.f + __expf(-zn));
    m[p] = xn[p] + r * hn[p];
    sm += m[p]; sq += m[p] * m[p];
  }
  float v2[2] = {sm, sq};
  blk_reduce<2>(v2, lds);
  float mum = v2[0] * inv, varm = v2[1] * inv - mum * mum;
  float rsm = rsqrtf(varm + 1e-5f);
#pragma unroll
  for (int p = 0; p < 3; ++p) {
    int i = tid + (p << 8);
    float nn = tanhf((m[p] - mum) * rsm * lw[1536 + i] + lb[1536 + i]);
    float hold = hcur[(size_t)b * 768 + i];
    float hnew = (1.f - z[p]) * nn + z[p] * hold;
    hcur[(size_t)b * 768 + i] = hnew;
    size_t o = ((size_t)b * 512 + t) * 768 + i;
    float rv = res[o];           // read before overwrite (layer 2 aliases)
    seq[o] = hnew + rv;
    if (is_last) hfin[(size_t)b * 768 + i] = hnew;
  }
}

__global__ void copy_f32(const float* __restrict__ s, float* __restrict__ d, int n) {
  int i = blockIdx.x * 256 + threadIdx.x;
  if (i < n) d[i] = s[i];
}

extern "C" void kernel_launch(void* const* d_in, const int* in_sizes, int n_in,
                              void* d_out, int out_size, void* d_ws, size_t ws_size,
                              hipStream_t stream) {
  const float* x    = (const float*)d_in[0];
  const float* h0   = (const float*)d_in[1];
  const float* w_ih = (const float*)d_in[2];
  const float* b_ih = (const float*)d_in[3];
  const float* w_hh = (const float*)d_in[4];
  const float* b_hh = (const float*)d_in[5];
  const float* lnw  = (const float*)d_in[6];
  const float* lnb  = (const float*)d_in[7];
  float* out = (float*)d_out;

  const int B = 64, T = 512, H = 768, G = 2304, L = 2;

  int CHUNK = 64;
  for (;;) {
    size_t need = ((size_t)B * CHUNK * G + (size_t)B * G + (size_t)B * H) * 4;
    if (need <= ws_size || CHUNK == 8) break;
    CHUNK >>= 1;
  }
  float* xg   = (float*)d_ws;
  float* hgws = xg + (size_t)B * CHUNK * G;
  float* hcur = hgws + (size_t)B * G;

  float* seq  = out;                      // [B][T][H]
  float* hfin = out + (size_t)B * T * H;  // [L][B][H]

  for (int l = 0; l < L; ++l) {
    const float* Wih = w_ih + (size_t)l * G * H;
    const float* Whh = w_hh + (size_t)l * G * H;
    const float* bih = b_ih + (size_t)l * G;
    const float* bhh = b_hh + (size_t)l * G;
    const float* lw  = lnw + (size_t)l * 3 * H;
    const float* lb  = lnb + (size_t)l * 3 * H;
    const float* src = (l == 0) ? x : seq;
    const float* res = (l == 0) ? x : seq;

    copy_f32<<<(B * H + 255) / 256, 256, 0, stream>>>(h0 + (size_t)l * B * H, hcur, B * H);

    for (int t0 = 0; t0 < T; t0 += CHUNK) {
      // precompute x-gates for this chunk: xg[b][tt][g]
      gemm_bt<<<dim3(G / 64, B), 256, 0, stream>>>(
          src + (size_t)t0 * H, (size_t)T * H, Wih, bih,
          xg, (size_t)CHUNK * G, CHUNK);
      for (int tt = 0; tt < CHUNK; ++tt) {
        int t = t0 + tt;
        gemm_bt<<<dim3(G / 64, 1), 256, 0, stream>>>(
            hcur, 0, Whh, bhh, hgws, 0, 64);
        step_update<<<B, 256, 0, stream>>>(
            hgws, xg, tt, CHUNK, lw, lb, hcur, res, seq, t,
            hfin + (size_t)l * B * H, (t == T - 1) ? 1 : 0);
      }
    }
  }
}